// Round 2
// baseline (179.063 us; speedup 1.0000x reference)
//
#include <hip/hip_runtime.h>

// Loss_8615704396494: masked L1 + 0.1 * bone-direction MSE over [B=128,T=1024,150] fp32.
// Memory-bound (157.3 MB read, scalar out).
//
// R7: occupancy, not sync. R5 (lockstep) and R6 (barrier-free) both landed ~60 us
// with every pipe idle (VALU 20%, LDS ~17%, HBM 16%) -> latency-bound from
// insufficient concurrency (16 waves/CU, LDS-capped at 4 blocks x 38.9 KB).
// Changes:
//  1. Span 8->4 rows/wave: LDS 19.2 KB/block -> 8 blocks/CU = 32 waves/CU (100%
//     occupancy), __launch_bounds__(256,8) to force VGPR<=64. Grid 2048, iters=4.
//  2. L1 folded into the bone pass via joint ownership (seg owns j0..j1-1, an exact
//     partition of the 50 joints). The prefetch registers die right after the
//     ds_writes, so next-span loads issue BEFORE compute and overlap it fully,
//     single-buffered. No barriers in the main loop (same-wave LDS ops in-order).

#define ROW_F    150
#define ROWS_PW  4                    // rows per wave-span
#define SPAN_F   (ROWS_PW * ROW_F)    // 600 floats per array per wave-span
#define SPAN_F4  (SPAN_F / 4)         // 150 float4
#define WAVES_PB 4
#define GRID     2048
#define TOTAL_WAVES (GRID * WAVES_PB) // 8192 waves; 32768 spans -> iters = 4

__global__ __launch_bounds__(256, 8) void loss_kernel(
    const float* __restrict__ preds,
    const float* __restrict__ targets,
    float* __restrict__ out,
    int iters, float inv_count)
{
    const float EPS = 1e-8f;
    __shared__ float sp[WAVES_PB][SPAN_F];
    __shared__ float st[WAVES_PB][SPAN_F];
    __shared__ float wsum[WAVES_PB];

    const int tid  = threadIdx.x;
    const int lane = tid & 63;
    const int wid  = tid >> 6;

    const float4* gp4 = reinterpret_cast<const float4*>(preds);
    const float4* gt4 = reinterpret_cast<const float4*>(targets);
    float4* sp4 = reinterpret_cast<float4*>(sp[wid]);
    float4* st4 = reinterpret_cast<float4*>(st[wid]);

    // Per-lane float4 slots within the wave's 150-float4 span: 2 full + 1 tail.
    const int g0 = lane, g1 = lane + 64, g2 = lane + 128;
    const bool w2 = (g2 < SPAN_F4);          // lane < 22
    const int g2c = w2 ? g2 : (SPAN_F4 - 1); // clamped (uniform flow, stays in VGPRs)

    // Compute mapping inside the wave: 4 rows x 16 segments.
    const int row = lane >> 4;               // 0..3
    const int seg = lane & 15;               // 0..15
    const int j0 = (seg < 2) ? seg * 4 : 8 + (seg - 2) * 3;  // segs 0,1: 4 bones; else 3
    const int j1 = j0 + ((seg < 2) ? 4 : 3);

    float l1 = 0.0f, mse = 0.0f;

    const int wglobal = blockIdx.x * WAVES_PB + wid;

    // Prologue prefetch: span = wglobal
    size_t sb = (size_t)wglobal * SPAN_F4;
    float4 rp0 = gp4[sb + g0], rp1 = gp4[sb + g1], rp2 = gp4[sb + g2c];
    float4 rt0 = gt4[sb + g0], rt1 = gt4[sb + g1], rt2 = gt4[sb + g2c];

    for (int it = 0; it < iters; ++it) {
        // regs -> private LDS slice (compiler inserts counted vmcnt waits here)
        sp4[g0] = rp0; st4[g0] = rt0;
        sp4[g1] = rp1; st4[g1] = rt1;
        if (w2) { sp4[g2] = rp2; st4[g2] = rt2; }

        // Registers are dead now -> issue next span's loads; they stay in flight
        // across the whole compute phase below.
        if (it + 1 < iters) {
            size_t nb = (size_t)(wglobal + (size_t)(it + 1) * TOTAL_WAVES) * SPAN_F4;
            rp0 = gp4[nb + g0]; rp1 = gp4[nb + g1]; rp2 = gp4[nb + g2c];
            rt0 = gt4[nb + g0]; rt1 = gt4[nb + g1]; rt2 = gt4[nb + g2c];
        }

        // ---- L1 + bone-direction MSE from the private LDS slice ----
        const float* rpb = &sp[wid][row * ROW_F];
        const float* rtb = &st[wid][row * ROW_F];

        float pmP[3], tmP[3];
#pragma unroll
        for (int c = 0; c < 3; ++c) {
            float t = rtb[3 * j0 + c];
            float p = rpb[3 * j0 + c];
            pmP[c] = (t != 0.0f) ? p : 0.0f;   // masked pred
            tmP[c] = t;                        // masked target == target
            l1 += fabsf(pmP[c] - tmP[c]);      // seg owns joint j0
        }

        for (int b = j0; b < j1; ++b) {
            int jn = b + 1;
            if (jn == 50) jn = 0;              // wrap bone (seg 15 last), wave-uniform
            float pmN[3], tmN[3];
#pragma unroll
            for (int c = 0; c < 3; ++c) {
                float t = rtb[3 * jn + c];
                float p = rpb[3 * jn + c];
                pmN[c] = (t != 0.0f) ? p : 0.0f;
                tmN[c] = t;
            }
            if (jn < j1 && jn != 0) {          // jn owned by this segment -> its L1 term
#pragma unroll
                for (int c = 0; c < 3; ++c) l1 += fabsf(pmN[c] - tmN[c]);
            }
            // bone: src = P (mask from tmP), dst = N
            float dp[3], dt[3], lp = 0.0f, lt = 0.0f;
#pragma unroll
            for (int c = 0; c < 3; ++c) {
                dp[c] = pmP[c] - pmN[c];
                dt[c] = tmP[c] - tmN[c];
                lp += dp[c] * dp[c];
                lt += dt[c] * dt[c];
            }
            float ip = __builtin_amdgcn_rcpf(__builtin_amdgcn_sqrtf(lp) + EPS);
            float iq = __builtin_amdgcn_rcpf(__builtin_amdgcn_sqrtf(lt) + EPS);
#pragma unroll
            for (int c = 0; c < 3; ++c) {
                float d = dp[c] * ip - dt[c] * iq;
                d = (tmP[c] != 0.0f) ? d : 0.0f;   // source-joint mask
                mse += d * d;
            }
#pragma unroll
            for (int c = 0; c < 3; ++c) { pmP[c] = pmN[c]; tmP[c] = tmN[c]; }
        }
    }

    // ---- Reduce: loss = (l1 + 0.1*mse) / COUNT ----
    float part = (l1 + 0.1f * mse) * inv_count;
#pragma unroll
    for (int off = 32; off > 0; off >>= 1)
        part += __shfl_down(part, off, 64);

    if (lane == 0) wsum[wid] = part;
    __syncthreads();                        // only barrier in the kernel
    if (tid == 0) {
        atomicAdd(out, wsum[0] + wsum[1] + wsum[2] + wsum[3]);
    }
}

extern "C" void kernel_launch(void* const* d_in, const int* in_sizes, int n_in,
                              void* d_out, int out_size, void* d_ws, size_t ws_size,
                              hipStream_t stream)
{
    const float* preds   = (const float*)d_in[0];
    const float* targets = (const float*)d_in[1];
    float* out = (float*)d_out;

    // d_out is re-poisoned to 0xAA before every timed launch — zero it (capture-safe).
    hipMemsetAsync(out, 0, sizeof(float) * out_size, stream);

    int n_elems = in_sizes[0];              // 128*1024*150 = 19,660,800
    int n_rows  = n_elems / ROW_F;          // 131072
    int spans   = n_rows / ROWS_PW;         // 32768
    float inv_count = 1.0f / (float)n_elems;

    int iters = spans / TOTAL_WAVES;        // 4
    loss_kernel<<<GRID, 256, 0, stream>>>(preds, targets, out, iters, inv_count);
}